// Round 3
// baseline (273.137 us; speedup 1.0000x reference)
//
#include <hip/hip_runtime.h>
#include <math.h>

#define NB 128
#define NT 512
#define NEDIM 128
#define NNEG 64
#define SCHUNK 16
#define NCHUNK (NT / SCHUNK)      // 32 chunks per batch row
#define NBLK (NB * NCHUNK)        // 4096 blocks
#define WSN (NBLK * 4)            // 16384 per-wave partials

typedef __bf16 bf16x8 __attribute__((ext_vector_type(8)));
typedef float  f32x4  __attribute__((ext_vector_type(4)));

__device__ __forceinline__ bf16x8 pack8(float4 v0, float4 v1) {
    bf16x8 o;
    o[0] = (__bf16)v0.x; o[1] = (__bf16)v0.y; o[2] = (__bf16)v0.z; o[3] = (__bf16)v0.w;
    o[4] = (__bf16)v1.x; o[5] = (__bf16)v1.y; o[6] = (__bf16)v1.z; o[7] = (__bf16)v1.w;
    return o;
}

// Fully register-resident: NO LDS, NO __syncthreads.
// M = 64 rows: m = 4*sloc + (i-1); wave w owns M-tile w (rows s0+4w..s0+4w+3,
// which are wave-private in mce -> A built straight from global).
// N: 64 negatives (tiles 0..3) + 32 pos cols (tiles 4,5; col j = base row s0+1+j,
// j<19 used).  K = 128 (e), 4 ksteps of 32.
// A-fragment lane (q,fl): row = s0+4w+(fl>>2), k = fl&3, e = kstep*32+q*8+j.
// Quad lanes (fl&3=0..3) load the SAME float4 (merged) and each keeps its k.
// B-fragment lane (q,fl): col-row's 32B at e0 = kstep*32+q*8 -> 2 float4 loads.
__launch_bounds__(256, 4)
__global__ void cpc_mfma_kernel(const float* __restrict__ base,        // (B,T,E)
                                const float* __restrict__ mce,         // (B,T,E,K)
                                const int*  __restrict__ seq_lens,     // (B)
                                const int*  __restrict__ sample_ids,   // (B,NNEG)
                                float* __restrict__ ws)                // (WSN)
{
    const int b    = blockIdx.y;
    const int s0   = blockIdx.x * SCHUNK;
    const int slot = (b * NCHUNK + blockIdx.x) * 4;
    const int L    = seq_lens[b];
    const float LOG65 = 4.1743873f;
    const float wgt[4] = {1.f/261632.f, 1.f/261120.f, 1.f/260608.f, 1.f/260096.f};

    // Fully-masked chunk: all-zero ce rows give loss = ln(65) analytically.
    if (s0 >= L) {
        if (threadIdx.x < 4) {
            float c = 0.f;
            #pragma unroll
            for (int i = 1; i <= 4; ++i) {
                int hi = min(SCHUNK, (NT - i) - s0);
                if (hi > 0) c += (float)hi * LOG65 * wgt[i - 1];
            }
            ws[slot + threadIdx.x] = (threadIdx.x == 0) ? c : 0.f;
        }
        return;
    }

    const int tid  = threadIdx.x;
    const int lane = tid & 63;
    const int w    = tid >> 6;
    const int q    = lane >> 4;
    const int fl   = lane & 15;
    const int k    = fl & 3;
    const bool c1  = (k & 1) != 0;
    const bool c2  = (k & 2) != 0;

    // A source row (wave-private): mce[b][s0 + 4w + (fl>>2)][e][k]
    const float4* arow4 = (const float4*)mce + (size_t)(b * NT + s0 + w * 4 + (fl >> 2)) * NEDIM;

    // B sources: 4 negative rows (gathered) + 2 positive rows per lane
    const float4* base4 = (const float4*)base;
    const float4* nrow[4];
    #pragma unroll
    for (int nt = 0; nt < 4; ++nt) {
        int r = sample_ids[b * NNEG + nt * 16 + fl];
        nrow[nt] = base4 + (size_t)r * (NEDIM / 4);
    }
    const float4* prow[2];
    #pragma unroll
    for (int t = 0; t < 2; ++t) {
        int srow = s0 + 1 + t * 16 + fl; if (srow > NT - 1) srow = NT - 1;  // clamped rows feed only non-taken rows
        prow[t] = base4 + (size_t)(b * NT + srow) * (NEDIM / 4);
    }

    f32x4 acc[6];
    #pragma unroll
    for (int nt = 0; nt < 6; ++nt) acc[nt] = (f32x4){0.f, 0.f, 0.f, 0.f};

    #pragma unroll
    for (int kstep = 0; kstep < 4; ++kstep) {
        const int e0  = kstep * 32 + q * 8;   // this lane's 8-e window
        const int e04 = kstep * 8 + q * 2;    // same, in float4 units

        // A fragment: 8 float4 loads (quad-merged), extract component k
        bf16x8 af;
        #pragma unroll
        for (int j = 0; j < 8; ++j) {
            float4 f = arow4[e0 + j];
            float lo = c1 ? f.y : f.x;
            float hi = c1 ? f.w : f.z;
            af[j] = (__bf16)(c2 ? hi : lo);
        }

        // B fragments: 32B contiguous per lane
        bf16x8 bv[6];
        #pragma unroll
        for (int nt = 0; nt < 4; ++nt)
            bv[nt] = pack8(nrow[nt][e04], nrow[nt][e04 + 1]);
        #pragma unroll
        for (int t = 0; t < 2; ++t)
            bv[4 + t] = pack8(prow[t][e04], prow[t][e04 + 1]);

        #pragma unroll
        for (int nt = 0; nt < 6; ++nt)
            acc[nt] = __builtin_amdgcn_mfma_f32_16x16x32_bf16(af, bv[nt], acc[nt], 0, 0, 0);
    }

    // ---- epilogue: extract positive from C, logsumexp over 65, masked mean ----
    const int sloc = w * 4 + q;           // = m>>2 for this thread's rows
    const int sg   = s0 + sloc;
    float lossacc = 0.f;
    #pragma unroll
    for (int r = 0; r < 4; ++r) {
        int ip   = r + 1;                 // m&3 == r
        int pcol = sloc + r;              // positive column within pos tiles
        float z0 = acc[0][r], z1 = acc[1][r];
        float z2 = acc[2][r], z3 = acc[3][r];
        float pv = (pcol < 16) ? acc[4][r] : acc[5][r];   // both reg names static
        float p  = __shfl(pv, (lane & 48) | (pcol & 15)); // grab col pcol's lane
        float mx = fmaxf(fmaxf(z0, z1), fmaxf(z2, z3));
        mx = fmaxf(mx, __shfl_xor(mx, 1));
        mx = fmaxf(mx, __shfl_xor(mx, 2));
        mx = fmaxf(mx, __shfl_xor(mx, 4));
        mx = fmaxf(mx, __shfl_xor(mx, 8));
        mx = fmaxf(mx, p);
        float es = __expf(z0 - mx) + __expf(z1 - mx)
                 + __expf(z2 - mx) + __expf(z3 - mx);
        es += __shfl_xor(es, 1);
        es += __shfl_xor(es, 2);
        es += __shfl_xor(es, 4);
        es += __shfl_xor(es, 8);
        es += __expf(p - mx);
        float loss = __logf(es) + (mx - p);
        loss = (sg < L) ? loss : LOG65;            // masked row => ln(65)
        bool take = (sg < NT - ip) && (fl == 0);   // valid (s,i); one lane per row
        lossacc += take ? wgt[r] * loss : 0.f;
    }
    lossacc += __shfl_xor(lossacc, 16);
    lossacc += __shfl_xor(lossacc, 32);
    if (lane == 0) ws[slot + w] = lossacc;         // per-wave partial
}

// Sum the 16384 per-wave partials -> out[0]. One block, no atomics.
__global__ void reduce_k(const float* __restrict__ ws, float* __restrict__ out) {
    const int tid = threadIdx.x;   // 256
    float s = 0.f;
    #pragma unroll
    for (int i = 0; i < WSN / 256; ++i) s += ws[tid + 256 * i];
    s += __shfl_xor(s, 1);
    s += __shfl_xor(s, 2);
    s += __shfl_xor(s, 4);
    s += __shfl_xor(s, 8);
    s += __shfl_xor(s, 16);
    s += __shfl_xor(s, 32);
    __shared__ float wsum[4];
    if ((tid & 63) == 0) wsum[tid >> 6] = s;
    __syncthreads();
    if (tid == 0) out[0] = wsum[0] + wsum[1] + wsum[2] + wsum[3];
}

extern "C" void kernel_launch(void* const* d_in, const int* in_sizes, int n_in,
                              void* d_out, int out_size, void* d_ws, size_t ws_size,
                              hipStream_t stream) {
    (void)in_sizes; (void)n_in; (void)out_size; (void)ws_size;
    const float* base       = (const float*)d_in[0];
    const float* mce        = (const float*)d_in[1];
    const int*   seq_lens   = (const int*)d_in[2];
    const int*   sample_ids = (const int*)d_in[3];
    float* out = (float*)d_out;
    float* ws  = (float*)d_ws;   // 16384 floats; every wave writes its slot

    dim3 grid(NCHUNK, NB);
    cpc_mfma_kernel<<<grid, 256, 0, stream>>>(base, mce, seq_lens, sample_ids, ws);
    reduce_k<<<1, 256, 0, stream>>>(ws, out);
}

// Round 4
// 224.709 us; speedup vs baseline: 1.2155x; 1.2155x over previous
//
#include <hip/hip_runtime.h>
#include <math.h>

#define NB 128
#define NT 512
#define NEDIM 128
#define NNEG 64
#define SCHUNK 16
#define CPB 4                     // chunks per block (persistent pipeline)
#define SBLK (SCHUNK * CPB)       // 64 s-rows per block
#define NXBLK (NT / SBLK)         // 8 x-blocks per batch row
#define NBLKS (NB * NXBLK)        // 1024 blocks
#define WSN (NBLKS * 4)           // 4096 per-wave partials

typedef __bf16 bf16x8 __attribute__((ext_vector_type(8)));
typedef float  f32x4  __attribute__((ext_vector_type(4)));

__device__ __forceinline__ bf16x8 pack8(float4 v0, float4 v1) {
    bf16x8 o;
    o[0] = (__bf16)v0.x; o[1] = (__bf16)v0.y; o[2] = (__bf16)v0.z; o[3] = (__bf16)v0.w;
    o[4] = (__bf16)v1.x; o[5] = (__bf16)v1.y; o[6] = (__bf16)v1.z; o[7] = (__bf16)v1.w;
    return o;
}

__device__ __forceinline__ float chunk_const(int s0c) {
    const float wgt[4] = {1.f/261632.f, 1.f/261120.f, 1.f/260608.f, 1.f/260096.f};
    const float LOG65 = 4.1743873f;
    float c = 0.f;
    #pragma unroll
    for (int i = 1; i <= 4; ++i) {
        int hi = min(SCHUNK, (NT - i) - s0c);
        if (hi > 0) c += (float)hi * LOG65 * wgt[i - 1];
    }
    return c;
}

// Persistent block: b = blockIdx.y, s-range [s0, s0+64) as 4 chunks of 16.
// Per chunk: M = 64 rows (m = 4*sloc + (i-1)), N = 64 negs + 32 pos cols,
// K = 128 (e) in 4 ksteps of 32.  Positives computed BY the MFMA (Pfrag col
// pcol = sloc+ip-1 in [0,19)) and pulled from the C tile via one shfl.
// B (negatives) staged ONCE per block; A/P double-buffered with the
// issue-early / write-late split so chunk c+1's HBM latency hides under
// chunk c's MFMA + epilogue.  LDS = 32 (A dbuf) + 16 (B) + 16 (P dbuf) = 64 KiB
// -> 2 blocks/CU, 8 waves.
__launch_bounds__(256, 2)
__global__ void cpc_mfma_kernel(const float* __restrict__ base,        // (B,T,E)
                                const float* __restrict__ mce,         // (B,T,E,K)
                                const int*  __restrict__ seq_lens,     // (B)
                                const int*  __restrict__ sample_ids,   // (B,NNEG)
                                float* __restrict__ ws)                // (WSN)
{
    const int b    = blockIdx.y;
    const int s0   = blockIdx.x * SBLK;
    const int slot = (b * NXBLK + blockIdx.x) * 4;
    const int L    = seq_lens[b];
    const float LOG65 = 4.1743873f;
    const float wgt[4] = {1.f/261632.f, 1.f/261120.f, 1.f/260608.f, 1.f/260096.f};

    // Whole block masked: analytic result for all 4 chunks.
    if (s0 >= L) {
        if (threadIdx.x < 4) {
            float c = 0.f;
            if (threadIdx.x == 0) {
                #pragma unroll
                for (int cc = 0; cc < CPB; ++cc) c += chunk_const(s0 + cc * SCHUNK);
            }
            ws[slot + threadIdx.x] = c;
        }
        return;
    }

    __shared__ __align__(16) __bf16 Afrag[2][1024 * 8];   // 32 KiB, xor ^(Cs&7)
    __shared__ __align__(16) __bf16 Bfrag[1024 * 8];      // 16 KiB, xor ^(eb&7)
    __shared__ __align__(16) __bf16 Pfrag[2][512 * 8];    // 16 KiB, xor ^(eb&7)

    const int tid  = threadIdx.x;
    const int lane = tid & 63;
    const int w    = tid >> 6;
    const int q    = lane >> 4;
    const int fl   = lane & 15;

    const float4* mce4  = (const float4*)mce;
    const float4* base4 = (const float4*)base;

    // ---- stage B (once): negatives, row-contiguous 16-lane groups ----
    #pragma unroll
    for (int it = 0; it < 4; ++it) {
        int h  = tid + 256 * it;          // (n, eb)
        int n  = h >> 4;
        int eb = h & 15;
        int r  = sample_ids[b * NNEG + n];
        const float4* srcb = base4 + (size_t)r * (NEDIM / 4) + eb * 2;
        float4 v0 = srcb[0], v1 = srcb[1];
        *(bf16x8*)(&Bfrag[(size_t)((eb * 64 + n) ^ (eb & 7)) * 8]) = pack8(v0, v1);
    }

    // ---- per-thread staging geometry ----
    const int sA  = tid & 15;             // A: row within chunk
    const int ebA = tid >> 4;             // A: e-block of 8
    const int CsS = (ebA >> 2) * 4 + (sA >> 2);
    const int bcA = CsS * 64 + (ebA & 3) * 16 + (sA & 3) * 4;
    const int xA  = CsS & 7;

    // ---- prologue: full stage of chunk 0 into buffer 0 ----
    {
        const float4* src = mce4 + (size_t)(b * NT + s0 + sA) * NEDIM + ebA * 8;
        float4 v[8];
        #pragma unroll
        for (int u = 0; u < 8; ++u) v[u] = src[u];
        const float* vf = (const float*)v;
        #pragma unroll
        for (int k = 0; k < 4; ++k) {
            bf16x8 o;
            #pragma unroll
            for (int u = 0; u < 8; ++u) o[u] = (__bf16)vf[4 * u + k];
            *(bf16x8*)(&Afrag[0][(size_t)((bcA + k) ^ xA) * 8]) = o;
        }
        #pragma unroll
        for (int it = 0; it < 2; ++it) {
            int h = tid + 256 * it;
            int j = h >> 4, ebP = h & 15;
            int srow = s0 + 1 + j; if (srow > NT - 1) srow = NT - 1;
            const float4* srcp = base4 + (size_t)(b * NT + srow) * (NEDIM / 4) + ebP * 2;
            *(bf16x8*)(&Pfrag[0][(size_t)((ebP * 32 + j) ^ (ebP & 7)) * 8]) = pack8(srcp[0], srcp[1]);
        }
    }
    __syncthreads();

    float lossacc = 0.f;
    const int sloc = w * 4 + q;           // m>>2 within chunk for this thread

    for (int c = 0; c < CPB; ++c) {
        const int s0c = s0 + c * SCHUNK;
        const bool vcur  = (s0c < L);
        const bool vnext = (c + 1 < CPB) && (s0 + (c + 1) * SCHUNK < L);

        // -- issue next chunk's global loads EARLY (T14 split) --
        float4 av[8];
        float4 pv0a, pv0b, pv1a, pv1b;
        if (vnext) {
            const int s0n = s0c + SCHUNK;
            const float4* src = mce4 + (size_t)(b * NT + s0n + sA) * NEDIM + ebA * 8;
            #pragma unroll
            for (int u = 0; u < 8; ++u) av[u] = src[u];
            {
                int j = tid >> 4, ebP = tid & 15;
                int srow = s0n + 1 + j; if (srow > NT - 1) srow = NT - 1;
                const float4* srcp = base4 + (size_t)(b * NT + srow) * (NEDIM / 4) + ebP * 2;
                pv0a = srcp[0]; pv0b = srcp[1];
            }
            {
                int h = tid + 256;
                int j = h >> 4, ebP = h & 15;
                int srow = s0n + 1 + j; if (srow > NT - 1) srow = NT - 1;
                const float4* srcp = base4 + (size_t)(b * NT + srow) * (NEDIM / 4) + ebP * 2;
                pv1a = srcp[0]; pv1b = srcp[1];
            }
        }

        // -- compute current chunk from buf[c&1] --
        if (vcur) {
            const __bf16* Ab = Afrag[c & 1];
            const __bf16* Pb = Pfrag[c & 1];
            f32x4 acc[6];
            #pragma unroll
            for (int nt = 0; nt < 6; ++nt) acc[nt] = (f32x4){0.f, 0.f, 0.f, 0.f};

            #pragma unroll
            for (int kstep = 0; kstep < 4; ++kstep) {
                int CsA = kstep * 4 + w;
                bf16x8 af = *(const bf16x8*)(&Ab[(size_t)(((CsA * 64 + lane) ^ (CsA & 7))) * 8]);
                int ebB = kstep * 4 + q;
                int xb  = ebB & 7;
                bf16x8 bv[6];
                #pragma unroll
                for (int nt = 0; nt < 4; ++nt)
                    bv[nt] = *(const bf16x8*)(&Bfrag[(size_t)(((ebB * 64 + nt * 16 + fl) ^ xb)) * 8]);
                #pragma unroll
                for (int t = 0; t < 2; ++t)
                    bv[4 + t] = *(const bf16x8*)(&Pb[(size_t)(((ebB * 32 + t * 16 + fl) ^ xb)) * 8]);
                #pragma unroll
                for (int nt = 0; nt < 6; ++nt)
                    acc[nt] = __builtin_amdgcn_mfma_f32_16x16x32_bf16(af, bv[nt], acc[nt], 0, 0, 0);
            }

            const int sg = s0c + sloc;
            #pragma unroll
            for (int r = 0; r < 4; ++r) {
                int ip   = r + 1;
                int pcol = sloc + r;
                float z0 = acc[0][r], z1 = acc[1][r];
                float z2 = acc[2][r], z3 = acc[3][r];
                float pv = (pcol < 16) ? acc[4][r] : acc[5][r];
                float p  = __shfl(pv, (lane & 48) | (pcol & 15));
                float mx = fmaxf(fmaxf(z0, z1), fmaxf(z2, z3));
                mx = fmaxf(mx, __shfl_xor(mx, 1));
                mx = fmaxf(mx, __shfl_xor(mx, 2));
                mx = fmaxf(mx, __shfl_xor(mx, 4));
                mx = fmaxf(mx, __shfl_xor(mx, 8));
                mx = fmaxf(mx, p);
                float es = __expf(z0 - mx) + __expf(z1 - mx)
                         + __expf(z2 - mx) + __expf(z3 - mx);
                es += __shfl_xor(es, 1);
                es += __shfl_xor(es, 2);
                es += __shfl_xor(es, 4);
                es += __shfl_xor(es, 8);
                es += __expf(p - mx);
                float loss = __logf(es) + (mx - p);
                loss = (sg < L) ? loss : LOG65;
                bool take = (sg < NT - ip) && (fl == 0);
                lossacc += take ? wgt[r] * loss : 0.f;
            }
        } else if (tid == 0) {
            lossacc += chunk_const(s0c);
        }
        __syncthreads();

        // -- write next chunk's fragments LATE into buf[(c+1)&1] --
        if (vnext) {
            __bf16* An = Afrag[(c + 1) & 1];
            __bf16* Pn = Pfrag[(c + 1) & 1];
            const float* vf = (const float*)av;
            #pragma unroll
            for (int k = 0; k < 4; ++k) {
                bf16x8 o;
                #pragma unroll
                for (int u = 0; u < 8; ++u) o[u] = (__bf16)vf[4 * u + k];
                *(bf16x8*)(&An[(size_t)((bcA + k) ^ xA) * 8]) = o;
            }
            {
                int j = tid >> 4, ebP = tid & 15;
                *(bf16x8*)(&Pn[(size_t)((ebP * 32 + j) ^ (ebP & 7)) * 8]) = pack8(pv0a, pv0b);
            }
            {
                int h = tid + 256;
                int j = h >> 4, ebP = h & 15;
                *(bf16x8*)(&Pn[(size_t)((ebP * 32 + j) ^ (ebP & 7)) * 8]) = pack8(pv1a, pv1b);
            }
        }
        __syncthreads();
    }

    lossacc += __shfl_xor(lossacc, 16);
    lossacc += __shfl_xor(lossacc, 32);
    if (lane == 0) ws[slot + w] = lossacc;
}

// Sum the 4096 per-wave partials -> out[0]. One block, no atomics.
__global__ void reduce_k(const float* __restrict__ ws, float* __restrict__ out) {
    const int tid = threadIdx.x;   // 256
    float s = 0.f;
    #pragma unroll
    for (int i = 0; i < WSN / 256; ++i) s += ws[tid + 256 * i];
    s += __shfl_xor(s, 1);
    s += __shfl_xor(s, 2);
    s += __shfl_xor(s, 4);
    s += __shfl_xor(s, 8);
    s += __shfl_xor(s, 16);
    s += __shfl_xor(s, 32);
    __shared__ float wsum[4];
    if ((tid & 63) == 0) wsum[tid >> 6] = s;
    __syncthreads();
    if (tid == 0) out[0] = wsum[0] + wsum[1] + wsum[2] + wsum[3];
}

extern "C" void kernel_launch(void* const* d_in, const int* in_sizes, int n_in,
                              void* d_out, int out_size, void* d_ws, size_t ws_size,
                              hipStream_t stream) {
    (void)in_sizes; (void)n_in; (void)out_size; (void)ws_size;
    const float* base       = (const float*)d_in[0];
    const float* mce        = (const float*)d_in[1];
    const int*   seq_lens   = (const int*)d_in[2];
    const int*   sample_ids = (const int*)d_in[3];
    float* out = (float*)d_out;
    float* ws  = (float*)d_ws;   // 4096 floats; every wave writes its slot

    dim3 grid(NXBLK, NB);
    cpc_mfma_kernel<<<grid, 256, 0, stream>>>(base, mce, seq_lens, sample_ids, ws);
    reduce_k<<<1, 256, 0, stream>>>(ws, out);
}

// Round 6
// 212.065 us; speedup vs baseline: 1.2880x; 1.0596x over previous
//
#include <hip/hip_runtime.h>
#include <math.h>

#define NB 128
#define NT 512
#define NEDIM 128
#define NNEG 64
#define SCHUNK 16
#define CPB 2                     // chunks per block; B staged once per pair
#define SBLK (SCHUNK * CPB)       // 32 s-rows per block
#define NXBLK (NT / SBLK)         // 16 x-blocks per batch row
#define NBLKS (NB * NXBLK)        // 2048 blocks
#define WSN (NBLKS * 4)           // 8192 per-wave partials

typedef __bf16 bf16x8 __attribute__((ext_vector_type(8)));
typedef float  f32x4  __attribute__((ext_vector_type(4)));

__device__ __forceinline__ bf16x8 pack8(float4 v0, float4 v1) {
    bf16x8 o;
    o[0] = (__bf16)v0.x; o[1] = (__bf16)v0.y; o[2] = (__bf16)v0.z; o[3] = (__bf16)v0.w;
    o[4] = (__bf16)v1.x; o[5] = (__bf16)v1.y; o[6] = (__bf16)v1.z; o[7] = (__bf16)v1.w;
    return o;
}

__device__ __forceinline__ float chunk_const(int s0c) {
    const float wgt[4] = {1.f/261632.f, 1.f/261120.f, 1.f/260608.f, 1.f/260096.f};
    const float LOG65 = 4.1743873f;
    float c = 0.f;
    #pragma unroll
    for (int i = 1; i <= 4; ++i) {
        int hi = min(SCHUNK, (NT - i) - s0c);
        if (hi > 0) c += (float)hi * LOG65 * wgt[i - 1];
    }
    return c;
}

// MFMA + epilogue for one 16-row chunk; returns this thread's loss partial.
// Fragment layouts identical to the verified R1 kernel (absmax 0).
__device__ __forceinline__ float compute_chunk(
    const __bf16* __restrict__ Af, const __bf16* __restrict__ Bf,
    const __bf16* __restrict__ Pf,
    int s0c, int L, int lane, int w, int q, int fl)
{
    const float LOG65 = 4.1743873f;
    const float wgt[4] = {1.f/261632.f, 1.f/261120.f, 1.f/260608.f, 1.f/260096.f};

    f32x4 acc[6];
    #pragma unroll
    for (int nt = 0; nt < 6; ++nt) acc[nt] = (f32x4){0.f, 0.f, 0.f, 0.f};

    #pragma unroll
    for (int kstep = 0; kstep < 4; ++kstep) {
        int CsA = kstep * 4 + w;
        bf16x8 af = *(const bf16x8*)(&Af[(size_t)(((CsA * 64 + lane) ^ (CsA & 7))) * 8]);
        int ebB = kstep * 4 + q;
        int xb  = ebB & 7;
        bf16x8 bv[6];
        #pragma unroll
        for (int nt = 0; nt < 4; ++nt)
            bv[nt] = *(const bf16x8*)(&Bf[(size_t)(((ebB * 64 + nt * 16 + fl) ^ xb)) * 8]);
        #pragma unroll
        for (int t = 0; t < 2; ++t)
            bv[4 + t] = *(const bf16x8*)(&Pf[(size_t)(((ebB * 32 + t * 16 + fl) ^ xb)) * 8]);
        #pragma unroll
        for (int nt = 0; nt < 6; ++nt)
            acc[nt] = __builtin_amdgcn_mfma_f32_16x16x32_bf16(af, bv[nt], acc[nt], 0, 0, 0);
    }

    const int sloc = w * 4 + q;
    const int sg   = s0c + sloc;
    float lossacc = 0.f;
    #pragma unroll
    for (int r = 0; r < 4; ++r) {
        int ip   = r + 1;
        int pcol = sloc + r;                              // in [0,19)
        float z0 = acc[0][r], z1 = acc[1][r];
        float z2 = acc[2][r], z3 = acc[3][r];
        float pv = (pcol < 16) ? acc[4][r] : acc[5][r];   // both names static
        float p  = __shfl(pv, (lane & 48) | (pcol & 15));
        float mx = fmaxf(fmaxf(z0, z1), fmaxf(z2, z3));
        mx = fmaxf(mx, __shfl_xor(mx, 1));
        mx = fmaxf(mx, __shfl_xor(mx, 2));
        mx = fmaxf(mx, __shfl_xor(mx, 4));
        mx = fmaxf(mx, __shfl_xor(mx, 8));
        mx = fmaxf(mx, p);
        float es = __expf(z0 - mx) + __expf(z1 - mx)
                 + __expf(z2 - mx) + __expf(z3 - mx);
        es += __shfl_xor(es, 1);
        es += __shfl_xor(es, 2);
        es += __shfl_xor(es, 4);
        es += __shfl_xor(es, 8);
        es += __expf(p - mx);
        float loss = __logf(es) + (mx - p);
        loss = (sg < L) ? loss : LOG65;
        bool take = (sg < NT - ip) && (fl == 0);
        lossacc += take ? wgt[r] * loss : 0.f;
    }
    return lossacc;
}

// R1 geometry (40 KiB LDS, 4 blocks/CU) + CPB=2: B staged once per block,
// chunk-1 A register-prefetched before chunk-0 compute (T14), P restaged
// (L2-hot).  3 barriers per 2 chunks vs R1's 2.
__launch_bounds__(256, 4)
__global__ void cpc_mfma_kernel(const float* __restrict__ base,        // (B,T,E)
                                const float* __restrict__ mce,         // (B,T,E,K)
                                const int*  __restrict__ seq_lens,     // (B)
                                const int*  __restrict__ sample_ids,   // (B,NNEG)
                                float* __restrict__ ws)                // (WSN)
{
    const int b    = blockIdx.y;
    const int s0   = blockIdx.x * SBLK;
    const int slot = (b * NXBLK + blockIdx.x) * 4;
    const int L    = seq_lens[b];

    // Whole block masked: analytic result for both chunks.
    if (s0 >= L) {
        if (threadIdx.x < 4) {
            float c = (threadIdx.x == 0)
                    ? chunk_const(s0) + chunk_const(s0 + SCHUNK) : 0.f;
            ws[slot + threadIdx.x] = c;
        }
        return;
    }

    __shared__ __align__(16) __bf16 Afrag[1024 * 8];   // 16 KiB, xor ^(Cs&7)
    __shared__ __align__(16) __bf16 Bfrag[1024 * 8];   // 16 KiB, xor ^(eb&7)
    __shared__ __align__(16) __bf16 Pfrag[512 * 8];    //  8 KiB, xor ^(eb&7)

    const int tid  = threadIdx.x;
    const int lane = tid & 63;
    const int w    = tid >> 6;
    const int q    = lane >> 4;
    const int fl   = lane & 15;

    const float4* mce4  = (const float4*)mce;
    const float4* base4 = (const float4*)base;

    // ---- stage B (once per block): negatives, 16-lane row groups ----
    #pragma unroll
    for (int it = 0; it < 4; ++it) {
        int h  = tid + 256 * it;          // (n, eb)
        int n  = h >> 4;
        int eb = h & 15;
        int r  = sample_ids[b * NNEG + n];
        const float4* srcb = base4 + (size_t)r * (NEDIM / 4) + eb * 2;
        float4 v0 = srcb[0], v1 = srcb[1];
        *(bf16x8*)(&Bfrag[(size_t)((eb * 64 + n) ^ (eb & 7)) * 8]) = pack8(v0, v1);
    }

    // ---- per-thread A staging geometry ----
    const int sA  = tid & 15;             // row within chunk
    const int ebA = tid >> 4;             // e-block of 8
    const int CsS = (ebA >> 2) * 4 + (sA >> 2);
    const int bcA = CsS * 64 + (ebA & 3) * 16 + (sA & 3) * 4;
    const int xA  = CsS & 7;

    // ---- stage A(c0): transpose k->row, f32->bf16 ----
    {
        const float4* src = mce4 + (size_t)(b * NT + s0 + sA) * NEDIM + ebA * 8;
        float4 v[8];
        #pragma unroll
        for (int u = 0; u < 8; ++u) v[u] = src[u];
        const float* vf = (const float*)v;
        #pragma unroll
        for (int k = 0; k < 4; ++k) {
            bf16x8 o;
            #pragma unroll
            for (int u = 0; u < 8; ++u) o[u] = (__bf16)vf[4 * u + k];
            *(bf16x8*)(&Afrag[(size_t)((bcA + k) ^ xA) * 8]) = o;
        }
    }
    // ---- stage P(c0): rows s0+1+j, j in [0,32) ----
    #pragma unroll
    for (int it = 0; it < 2; ++it) {
        int h = tid + 256 * it;
        int j = h >> 4, ebP = h & 15;
        int srow = s0 + 1 + j; if (srow > NT - 1) srow = NT - 1;
        const float4* srcp = base4 + (size_t)(b * NT + srow) * (NEDIM / 4) + ebP * 2;
        *(bf16x8*)(&Pfrag[(size_t)((ebP * 32 + j) ^ (ebP & 7)) * 8]) = pack8(srcp[0], srcp[1]);
    }
    __syncthreads();

    const int  s1 = s0 + SCHUNK;
    const bool v1 = (s1 < L);

    // ---- T14: issue chunk-1 A loads EARLY (HBM latency hides under c0) ----
    float4 av[8];
    if (v1) {
        const float4* src = mce4 + (size_t)(b * NT + s1 + sA) * NEDIM + ebA * 8;
        #pragma unroll
        for (int u = 0; u < 8; ++u) av[u] = src[u];
    }

    float lossacc = compute_chunk(Afrag, Bfrag, Pfrag, s0, L, lane, w, q, fl);

    if (v1) {
        __syncthreads();                  // all reads of A(c0)/P(c0) done
        {
            const float* vf = (const float*)av;
            #pragma unroll
            for (int k = 0; k < 4; ++k) {
                bf16x8 o;
                #pragma unroll
                for (int u = 0; u < 8; ++u) o[u] = (__bf16)vf[4 * u + k];
                *(bf16x8*)(&Afrag[(size_t)((bcA + k) ^ xA) * 8]) = o;
            }
        }
        #pragma unroll
        for (int it = 0; it < 2; ++it) {  // restage P for c1 (rows L2-hot)
            int h = tid + 256 * it;
            int j = h >> 4, ebP = h & 15;
            int srow = s1 + 1 + j; if (srow > NT - 1) srow = NT - 1;
            const float4* srcp = base4 + (size_t)(b * NT + srow) * (NEDIM / 4) + ebP * 2;
            *(bf16x8*)(&Pfrag[(size_t)((ebP * 32 + j) ^ (ebP & 7)) * 8]) = pack8(srcp[0], srcp[1]);
        }
        __syncthreads();
        lossacc += compute_chunk(Afrag, Bfrag, Pfrag, s1, L, lane, w, q, fl);
    } else if (tid == 0) {
        lossacc += chunk_const(s1);       // chunk 1 fully masked
    }

    lossacc += __shfl_xor(lossacc, 16);
    lossacc += __shfl_xor(lossacc, 32);
    if (lane == 0) ws[slot + w] = lossacc;
}

// Sum the 8192 per-wave partials -> out[0]. One block, no atomics.
__global__ void reduce_k(const float* __restrict__ ws, float* __restrict__ out) {
    const int tid = threadIdx.x;   // 256
    float s = 0.f;
    #pragma unroll
    for (int i = 0; i < WSN / 256; ++i) s += ws[tid + 256 * i];
    s += __shfl_xor(s, 1);
    s += __shfl_xor(s, 2);
    s += __shfl_xor(s, 4);
    s += __shfl_xor(s, 8);
    s += __shfl_xor(s, 16);
    s += __shfl_xor(s, 32);
    __shared__ float wsum[4];
    if ((tid & 63) == 0) wsum[tid >> 6] = s;
    __syncthreads();
    if (tid == 0) out[0] = wsum[0] + wsum[1] + wsum[2] + wsum[3];
}

extern "C" void kernel_launch(void* const* d_in, const int* in_sizes, int n_in,
                              void* d_out, int out_size, void* d_ws, size_t ws_size,
                              hipStream_t stream) {
    (void)in_sizes; (void)n_in; (void)out_size; (void)ws_size;
    const float* base       = (const float*)d_in[0];
    const float* mce        = (const float*)d_in[1];
    const int*   seq_lens   = (const int*)d_in[2];
    const int*   sample_ids = (const int*)d_in[3];
    float* out = (float*)d_out;
    float* ws  = (float*)d_ws;   // 8192 floats; every wave writes its slot

    dim3 grid(NXBLK, NB);
    cpc_mfma_kernel<<<grid, 256, 0, stream>>>(base, mce, seq_lens, sample_ids, ws);
    reduce_k<<<1, 256, 0, stream>>>(ws, out);
}